// Round 1
// 278.418 us; speedup vs baseline: 1.0152x; 1.0152x over previous
//
#include <hip/hip_runtime.h>
#include <cstdint>
#include <cstddef>

// B=16, N=1024, D=768, H=12, HS=64, L=2
// R7 changes vs R6:
//  - gemm1/gemmf ported to 256x256 / BK=64 / 8-wave / 8-phase counted-vmcnt
//    schedule (T2 swizzle + T3/T4 8-phase + T5 setprio). 128KB dynamic LDS,
//    1 block/CU, 192 blocks. Race-freedom of the staging schedule verified
//    region-by-region (see comments in gemm256).
//  - circ kernel unchanged (ported next round if this verifies).
//
// ws layout (bytes): unchanged from R6.
//  [0, 25165824)          slotA : xn_bf16 -> z1_bf16
//  [25165824, 50331648)   Vt    : gemm1 out ; reused as gbf after circ
//  [50331648, 75497472)   slotX : x2_bf16 (circ out, read by gemmf1 + final)
//  [75497472, 76677120)   W2t
//  [76677120, 79036416)   Wft

typedef __attribute__((ext_vector_type(8))) short bf16x8;
typedef __attribute__((ext_vector_type(4))) float f32x4;
typedef __attribute__((ext_vector_type(4))) unsigned short us4;

__device__ __forceinline__ unsigned short f2bf(float f) {
  unsigned int u = __builtin_bit_cast(unsigned int, f);
  u += 0x7FFFu + ((u >> 16) & 1u);
  return (unsigned short)(u >> 16);
}
__device__ __forceinline__ float bf2f(unsigned short u) {
  return __builtin_bit_cast(float, (unsigned int)u << 16);
}

__device__ __forceinline__ void g2l16(const void* g, void* l) {
  __builtin_amdgcn_global_load_lds(
      (const __attribute__((address_space(1))) unsigned int*)g,
      (__attribute__((address_space(3))) unsigned int*)l,
      16, 0, 0);
}

// raw barrier: wait for all but n outstanding vmem, all lds ops, then barrier.
#define WAITB(n) asm volatile("s_waitcnt vmcnt(" #n ") lgkmcnt(0)\n\ts_barrier" ::: "memory")
#define BARX asm volatile("s_waitcnt lgkmcnt(0)\n\ts_barrier" ::: "memory")
#define BARV(n) asm volatile("s_waitcnt vmcnt(" #n ") lgkmcnt(0)\n\ts_barrier" ::: "memory")

// ---------------- pack kernels ----------------
__global__ __launch_bounds__(256) void pack_w2t(const float* __restrict__ Wv,
                                                unsigned short* __restrict__ W2t) {
  int o = blockIdx.x * 256 + threadIdx.x;
  int np = o / 768, d = o - np * 768;
  int h = np >> 6, k = np & 63;
  W2t[o] = f2bf(Wv[h * 49152 + d * 64 + k]);
}

__global__ __launch_bounds__(256) void pack_wft(const float* __restrict__ Wf,
                                                unsigned short* __restrict__ Wft) {
  int o = blockIdx.x * 256 + threadIdx.x;
  int l = o / 589824, rem = o - l * 589824;
  int np = rem / 768, d = rem - np * 768;
  Wft[o] = f2bf(Wf[l * 589824 + d * 768 + np]);
}

// ---------------- row kernels ----------------
__device__ __forceinline__ void wave_reduce2(float& s, float& s2) {
#pragma unroll
  for (int off = 32; off > 0; off >>= 1) {
    s += __shfl_down(s, off);
    s2 += __shfl_down(s2, off);
  }
  s = __shfl(s, 0);
  s2 = __shfl(s2, 0);
}

__global__ __launch_bounds__(256) void ln1_kernel(const float* __restrict__ x,
                                                  const float* __restrict__ sc,
                                                  const float* __restrict__ bi,
                                                  unsigned short* __restrict__ out) {
  int row = blockIdx.x * 4 + (threadIdx.x >> 6);
  int lane = threadIdx.x & 63;
  size_t base = (size_t)row * 768;
  float4 v[3];
#pragma unroll
  for (int j = 0; j < 3; ++j) v[j] = *(const float4*)(x + base + lane * 4 + j * 256);
  float s = 0.f, s2 = 0.f;
#pragma unroll
  for (int j = 0; j < 3; ++j) {
    s += v[j].x + v[j].y + v[j].z + v[j].w;
    s2 += v[j].x * v[j].x + v[j].y * v[j].y + v[j].z * v[j].z + v[j].w * v[j].w;
  }
  wave_reduce2(s, s2);
  float mu = s * (1.0f / 768.0f);
  float var = s2 * (1.0f / 768.0f) - mu * mu;
  float r = rsqrtf(var + 1e-6f);
#pragma unroll
  for (int j = 0; j < 3; ++j) {
    int d = lane * 4 + j * 256;
    float4 scv = *(const float4*)(sc + d);
    float4 biv = *(const float4*)(bi + d);
    us4 o;
    o[0] = f2bf((v[j].x - mu) * r * scv.x + biv.x);
    o[1] = f2bf((v[j].y - mu) * r * scv.y + biv.y);
    o[2] = f2bf((v[j].z - mu) * r * scv.z + biv.z);
    o[3] = f2bf((v[j].w - mu) * r * scv.w + biv.w);
    *(us4*)(out + base + d) = o;
  }
}

// g is bf16
__global__ __launch_bounds__(256) void lnswish_kernel(const unsigned short* __restrict__ g,
                                                      const float* __restrict__ sc,
                                                      const float* __restrict__ bi,
                                                      unsigned short* __restrict__ out) {
  int row = blockIdx.x * 4 + (threadIdx.x >> 6);
  int lane = threadIdx.x & 63;
  size_t base = (size_t)row * 768;
  float v[3][4];
#pragma unroll
  for (int j = 0; j < 3; ++j) {
    us4 gv = *(const us4*)(g + base + lane * 4 + j * 256);
#pragma unroll
    for (int q = 0; q < 4; ++q) v[j][q] = bf2f(gv[q]);
  }
  float s = 0.f, s2 = 0.f;
#pragma unroll
  for (int j = 0; j < 3; ++j)
#pragma unroll
    for (int q = 0; q < 4; ++q) { s += v[j][q]; s2 += v[j][q] * v[j][q]; }
  wave_reduce2(s, s2);
  float mu = s * (1.0f / 768.0f);
  float var = s2 * (1.0f / 768.0f) - mu * mu;
  float r = rsqrtf(var + 1e-6f);
#pragma unroll
  for (int j = 0; j < 3; ++j) {
    int d = lane * 4 + j * 256;
    float4 scv = *(const float4*)(sc + d);
    float4 biv = *(const float4*)(bi + d);
    const float* scp = &scv.x;
    const float* bip = &biv.x;
    us4 o;
#pragma unroll
    for (int q = 0; q < 4; ++q) {
      float z = (v[j][q] - mu) * r * scp[q] + bip[q];
      o[q] = f2bf(z / (1.0f + __expf(-z)));
    }
    *(us4*)(out + base + d) = o;
  }
}

// g bf16, x2 bf16 -> out f32
__global__ __launch_bounds__(256) void final_kernel(const unsigned short* __restrict__ g,
                                                    const float* __restrict__ sc,
                                                    const float* __restrict__ bi,
                                                    const unsigned short* __restrict__ x2,
                                                    float* __restrict__ out) {
  int row = blockIdx.x * 4 + (threadIdx.x >> 6);
  int lane = threadIdx.x & 63;
  size_t base = (size_t)row * 768;
  float v[3][4];
#pragma unroll
  for (int j = 0; j < 3; ++j) {
    us4 gv = *(const us4*)(g + base + lane * 4 + j * 256);
#pragma unroll
    for (int q = 0; q < 4; ++q) v[j][q] = bf2f(gv[q]);
  }
  float s = 0.f, s2 = 0.f;
#pragma unroll
  for (int j = 0; j < 3; ++j)
#pragma unroll
    for (int q = 0; q < 4; ++q) { s += v[j][q]; s2 += v[j][q] * v[j][q]; }
  wave_reduce2(s, s2);
  float mu = s * (1.0f / 768.0f);
  float var = s2 * (1.0f / 768.0f) - mu * mu;
  float r = rsqrtf(var + 1e-6f);
#pragma unroll
  for (int j = 0; j < 3; ++j) {
    int d = lane * 4 + j * 256;
    float4 scv = *(const float4*)(sc + d);
    float4 biv = *(const float4*)(bi + d);
    us4 xv = *(const us4*)(x2 + base + d);
    const float* scp = &scv.x;
    const float* bip = &biv.x;
    float4 o;
    float* op = &o.x;
#pragma unroll
    for (int q = 0; q < 4; ++q) {
      float z = (v[j][q] - mu) * r * scp[q] + bip[q];
      float sw = z / (1.0f + __expf(-z));
      float t = sw + bf2f(xv[q]);
      float ax = fabsf(t);
      op[q] = ax + __logf(1.0f + __expf(-2.0f * ax)) - 0.69314718055994531f;
    }
    *(float4*)(out + base + d) = o;
  }
}

// ---------- 256x256 8-phase GEMM core (BK=64, 8 waves, 2 LDS buffers) ------
// Wave map: wm = (wid>>2)*64, wn = (wid&3)*32.
//  A m-half mh covers LDS rows [mh*128, mh*128+128) (contiguous across waves).
//  B n-half nh covers LDS rows [nh*128, nh*128+128).
// LDS (shorts): buf b at b*32768; A [0,16384), B [16384,32768). Row stride 64
// shorts (128B), 8x16B slots per row, slot XOR-swizzled with (row&7) (T2).
// Staged via g2l16 with linear LDS dest (tid*16B) + inverse-swizzled global
// source (rule #21). Frag reads: 16 rows x 4 fq -> 8 banks x 2 = 2-way (free).
//
// Phase order per K-tile: P+0 (mh0,nh0), P+1 (mh0,nh1), P+2 (mh1,nh0),
// P+3 (mh1,nh1). A-frags cached per mh (loaded P+0/P+2), B all cached
// (nh0 at P+0, nh1 at P+1). LDS-read completion per region:
//   A01 after P+0, B01 after P+0, B23 after P+1, A23 after P+2.
// Staging schedule per iter t (computes tiles 2t->buf0 in P0-3, 2t+1->buf1
// in P4-7; 2 calls/phase; every target region has >=2 barrier-separated
// phases since its last LDS read; BARX includes lgkmcnt(0) so reads complete
// before each barrier):
//   P0: (2t+1).A23->buf1   P1: (2t+1).B23->buf1
//   P2: (2t+2).A01->buf0   P3: (2t+2).B01->buf0
//   P4: (2t+2).A23->buf0   P5: (2t+2).B23->buf0
//   P6: (2t+3).A01->buf1   P7: (2t+3).B01->buf1
// Waits (counted, never 0 mid-loop):
//   end-P3: vmcnt(4) -> tile 2t+1 fully landed (P2,P3's 4 calls may fly)
//   end-P7: vmcnt(4) -> tile 2t+2 fully landed (P6,P7's 4 calls may fly)
template <int K>
__device__ __forceinline__ void gemm256(const unsigned short* __restrict__ A,
                                        const unsigned short* __restrict__ Bt,
                                        int m0, int n0, unsigned short* lds,
                                        f32x4 acc[8][4]) {
  const int tid = threadIdx.x;
  const int lane = tid & 63;
  const int wid = tid >> 6;
  const int wm = (wid >> 2) << 6;
  const int wn = (wid & 3) << 5;
  const int fm = lane & 15, fq = lane >> 4;
  const int srow = tid >> 3;                    // staging row within call
  const int sslot = (tid & 7) ^ (srow & 7);     // inverse-swizzled source slot
  const size_t abase = (size_t)(m0 + srow) * K + (sslot << 3);
  const size_t bbase = (size_t)(n0 + srow) * K + (sslot << 3);

  bf16x8 aq[4][2], bq[4][2];

#define STG_A(kt, bb, c)                                                     \
  g2l16(A + abase + (size_t)((c) << 6) * K + ((kt) << 6),                    \
        lds + ((bb) << 15) + ((c) << 12) + (tid << 3))
#define STG_B(kt, bb, c)                                                     \
  g2l16(Bt + bbase + (size_t)((c) << 6) * K + ((kt) << 6),                   \
        lds + ((bb) << 15) + 16384 + ((c) << 12) + (tid << 3))
#define LDA(bb, mh)                                                          \
  _Pragma("unroll") for (int mt = 0; mt < 4; ++mt) {                         \
    const unsigned short* p =                                                \
        lds + ((bb) << 15) + (wm + ((mh) << 7) + (mt << 4) + fm) * 64;       \
    _Pragma("unroll") for (int kk = 0; kk < 2; ++kk)                         \
      aq[mt][kk] = *(const bf16x8*)(p + ((((kk << 2) + fq) ^ (fm & 7)) << 3)); \
  }
#define LDB(bb, nh)                                                          \
  _Pragma("unroll") for (int nt = 0; nt < 2; ++nt) {                         \
    const unsigned short* p = lds + ((bb) << 15) + 16384 +                   \
                              (wn + ((nh) << 7) + (nt << 4) + fm) * 64;      \
    _Pragma("unroll") for (int kk = 0; kk < 2; ++kk)                         \
      bq[((nh) << 1) + nt][kk] =                                             \
          *(const bf16x8*)(p + ((((kk << 2) + fq) ^ (fm & 7)) << 3));        \
  }
#define MMX(mh, nh)                                                          \
  {                                                                          \
    __builtin_amdgcn_s_setprio(1);                                           \
    _Pragma("unroll") for (int mt = 0; mt < 4; ++mt)                         \
    _Pragma("unroll") for (int nt = 0; nt < 2; ++nt)                         \
    _Pragma("unroll") for (int kk = 0; kk < 2; ++kk)                         \
      acc[((mh) << 2) + mt][((nh) << 1) + nt] =                              \
          __builtin_amdgcn_mfma_f32_16x16x32_bf16(                           \
              aq[mt][kk], bq[((nh) << 1) + nt][kk],                          \
              acc[((mh) << 2) + mt][((nh) << 1) + nt], 0, 0, 0);             \
    __builtin_amdgcn_s_setprio(0);                                           \
  }

  constexpr int NT = K >> 6;  // K-tiles (must be even, >=4)
  // prologue: tile0 full -> buf0; tile1 A01,B01 -> buf1 (12 calls)
  STG_A(0, 0, 0); STG_A(0, 0, 1); STG_A(0, 0, 2); STG_A(0, 0, 3);
  STG_B(0, 0, 0); STG_B(0, 0, 1); STG_B(0, 0, 2); STG_B(0, 0, 3);
  STG_A(1, 1, 0); STG_A(1, 1, 1);
  STG_B(1, 1, 0); STG_B(1, 1, 1);
  BARV(4);  // tile0's 8 landed; tile1's 4 in flight

  for (int t = 0; t < (NT >> 1) - 1; ++t) {
    const int k1 = 2 * t + 1, k2 = 2 * t + 2, k3 = 2 * t + 3;
    // P0
    LDA(0, 0); LDB(0, 0);
    STG_A(k1, 1, 2); STG_A(k1, 1, 3);
    MMX(0, 0); BARX;
    // P1
    LDB(0, 1);
    STG_B(k1, 1, 2); STG_B(k1, 1, 3);
    MMX(0, 1); BARX;
    // P2
    LDA(0, 1);
    STG_A(k2, 0, 0); STG_A(k2, 0, 1);
    MMX(1, 0); BARX;
    // P3
    STG_B(k2, 0, 0); STG_B(k2, 0, 1);
    MMX(1, 1); BARV(4);
    // P4
    LDA(1, 0); LDB(1, 0);
    STG_A(k2, 0, 2); STG_A(k2, 0, 3);
    MMX(0, 0); BARX;
    // P5
    LDB(1, 1);
    STG_B(k2, 0, 2); STG_B(k2, 0, 3);
    MMX(0, 1); BARX;
    // P6
    LDA(1, 1);
    STG_A(k3, 1, 0); STG_A(k3, 1, 1);
    MMX(1, 0); BARX;
    // P7
    STG_B(k3, 1, 0); STG_B(k3, 1, 1);
    MMX(1, 1); BARV(4);
  }
  // peeled last iter: tiles NT-2 (buf0), NT-1 (buf1); no staging past NT-1
  {
    const int k1 = NT - 1;
    LDA(0, 0); LDB(0, 0);
    STG_A(k1, 1, 2); STG_A(k1, 1, 3);
    MMX(0, 0); BARX;
    LDB(0, 1);
    STG_B(k1, 1, 2); STG_B(k1, 1, 3);
    MMX(0, 1); BARX;
    LDA(0, 1);
    MMX(1, 0); BARX;
    MMX(1, 1);
    BARV(0);  // drain: tile NT-1's A01/B01 + A23/B23 all landed
    LDA(1, 0); LDB(1, 0);
    MMX(0, 0); BARX;
    LDB(1, 1);
    MMX(0, 1); BARX;
    LDA(1, 1);
    MMX(1, 0); BARX;
    MMX(1, 1);
  }
#undef STG_A
#undef STG_B
#undef LDA
#undef LDB
#undef MMX
}

__device__ __forceinline__ void decode256(int bid, int& m0, int& n0) {
  // 192 blocks, 192%8==0 -> bijective XCD swizzle, 24 contiguous wgids/XCD
  int wg = (bid & 7) * 24 + (bid >> 3);
  int mi = wg / 3, ni = wg - mi * 3;
  m0 = mi << 8;
  n0 = ni << 8;
}

// GEMM1: xn @ W2t -> Vt[h][b*64+k][n] (bf16)
__global__ __launch_bounds__(512, 2) void gemm1_256(const unsigned short* __restrict__ A,
                                                    const unsigned short* __restrict__ W2t,
                                                    unsigned short* __restrict__ Vt) {
  extern __shared__ unsigned short lds[];
  f32x4 acc[8][4] = {};
  int m0, n0;
  decode256(blockIdx.x, m0, n0);
  gemm256<768>(A, W2t, m0, n0, lds, acc);
  const int lane = threadIdx.x & 63, wid = threadIdx.x >> 6;
  const int wm = (wid >> 2) << 6, wn = (wid & 3) << 5;
  const int fm = lane & 15, fq = lane >> 4;
#pragma unroll
  for (int ai = 0; ai < 8; ++ai) {
    int rowb = m0 + wm + ((ai >> 2) << 7) + ((ai & 3) << 4) + (fq << 2);
    int b = rowb >> 10, n = rowb & 1023;
#pragma unroll
    for (int nj = 0; nj < 4; ++nj) {
      int col = n0 + wn + ((nj >> 1) << 7) + ((nj & 1) << 4) + fm;
      int h = col >> 6, ck = col & 63;
      size_t off = ((size_t)h << 20) + (size_t)((b << 6) + ck) * 1024 + n;
      us4 v;
#pragma unroll
      for (int r = 0; r < 4; ++r) v[r] = f2bf(acc[ai][nj][r]);
      *(us4*)(Vt + off) = v;
    }
  }
}

// FFN GEMM: A(bf16) @ Wt + bias -> g (bf16)
__global__ __launch_bounds__(512, 2) void gemmf_256(const unsigned short* __restrict__ A,
                                                    const unsigned short* __restrict__ Bt,
                                                    const float* __restrict__ bias,
                                                    unsigned short* __restrict__ g) {
  extern __shared__ unsigned short lds[];
  f32x4 acc[8][4] = {};
  int m0, n0;
  decode256(blockIdx.x, m0, n0);
  gemm256<768>(A, Bt, m0, n0, lds, acc);
  const int lane = threadIdx.x & 63, wid = threadIdx.x >> 6;
  const int wm = (wid >> 2) << 6, wn = (wid & 3) << 5;
  const int fm = lane & 15, fq = lane >> 4;
#pragma unroll
  for (int ai = 0; ai < 8; ++ai) {
    int rowb = m0 + wm + ((ai >> 2) << 7) + ((ai & 3) << 4) + (fq << 2);
#pragma unroll
    for (int nj = 0; nj < 4; ++nj) {
      int col = n0 + wn + ((nj >> 1) << 7) + ((nj & 1) << 4) + fm;
      float bc = bias[col];
#pragma unroll
      for (int r = 0; r < 4; ++r)
        g[(size_t)(rowb + r) * 768 + col] = f2bf(acc[ai][nj][r] + bc);
    }
  }
}

// circGEMM: A from alpha (circulant, LDS-resident shifted copies), B = Vt_h
// epilogue: x2 = x + y, bf16 only.  (unchanged from R6)
__global__ __launch_bounds__(256, 3) void circ_kernel(const float* __restrict__ alpha,
                                                      const unsigned short* __restrict__ Vt,
                                                      const float* __restrict__ xin,
                                                      unsigned short* __restrict__ x2bf) {
  __shared__ unsigned short sAc[8 * 1168];   // 8 shift-copies of alpha window
  __shared__ unsigned short sB[4 * 4096];    // 4-deep B pipeline
  f32x4 acc[4][4] = {};
  int f = blockIdx.x;
  int xcd = f & 7, s = f >> 3;
  int h = s >> 3, t = s & 7;
  int mr = xcd >> 1, nr = xcd & 1;
  int m0 = ((mr << 1) + (t >> 2)) << 7;
  int n0 = ((nr << 2) + (t & 3)) << 7;

  const int tid = threadIdx.x;
  const int wave = tid >> 6, lane = tid & 63;
  const int wm = (wave >> 1) << 6, wn = (wave & 1) << 6;
  const int fm = lane & 15, fq = lane >> 4;

  const float* ah = alpha + (h << 10);
#pragma unroll
  for (int c = 0; c < 8; ++c)
    for (int u = tid; u < 1160; u += 256)
      sAc[c * 1168 + u] = f2bf(ah[(m0 - 897 - u - c) & 1023]);
  asm volatile("s_waitcnt vmcnt(0)" ::: "memory");  // flush fill loads from vmcnt

  const unsigned short* Bt = Vt + ((size_t)h << 20);
  const int r0 = tid >> 2, r1 = r0 + 64;
  const int cg = tid & 3;
  const int cs0 = (cg ^ ((r0 >> 1) & 3)) << 3;
  const int cs1 = (cg ^ ((r1 >> 1) & 3)) << 3;
  const int ld0 = r0 * 32 + (cg << 3);
  const int ld1 = r1 * 32 + (cg << 3);

#define STAGEB(k0v, buf)                                                      \
  {                                                                           \
    unsigned short* dB = sB + (buf) * 4096;                                   \
    g2l16(Bt + (size_t)(n0 + r0) * 1024 + (k0v) + cs0, dB + ld0);             \
    g2l16(Bt + (size_t)(n0 + r1) * 1024 + (k0v) + cs1, dB + ld1);             \
  }
#define CCOMP(it)                                                             \
  {                                                                           \
    const unsigned short* pB = sB + ((it) & 3) * 4096;                        \
    int k0v = (it) << 5;                                                      \
    bf16x8 aq[4], bq[4];                                                      \
    _Pragma("unroll") for (int t_ = 0; t_ < 4; ++t_) {                        \
      int rl = wm + (t_ << 4) + fm;                                           \
      int d = k0v + (fq << 3) + 127 - rl;                                     \
      int c = d & 7;                                                          \
      aq[t_] = *(const bf16x8*)(sAc + c * 1168 + (d - c));                    \
      int rb = wn + (t_ << 4) + fm;                                           \
      bq[t_] = *(const bf16x8*)(pB + (rb << 5) + ((fq ^ ((rb >> 1) & 3)) << 3)); \
    }                                                                         \
    _Pragma("unroll") for (int mt = 0; mt < 4; ++mt)                          \
    _Pragma("unroll") for (int nt = 0; nt < 4; ++nt)                          \
      acc[mt][nt] = __builtin_amdgcn_mfma_f32_16x16x32_bf16(aq[mt], bq[nt],   \
                                                            acc[mt][nt], 0, 0, 0); \
  }

  STAGEB(0, 0);
  STAGEB(32, 1);
  STAGEB(64, 2);
  for (int it = 0; it < 30; ++it) {
    WAITB(4);                     // stage(it) landed; it+1, it+2 in flight
    if (it < 29) STAGEB((it + 3) << 5, (it + 3) & 3);
    CCOMP(it);
  }
  WAITB(2);
  CCOMP(30);
  WAITB(0);
  CCOMP(31);
#undef STAGEB

  // epilogue: x2 = x + y (bf16)
#pragma unroll
  for (int mt = 0; mt < 4; ++mt) {
    int ib = m0 + wm + (mt << 4) + (fq << 2);
#pragma unroll
    for (int nt = 0; nt < 4; ++nt) {
      int c = n0 + wn + (nt << 4) + fm;
      int b = c >> 6, k = c & 63;
      size_t off = ((size_t)(b << 10) + ib) * 768 + (h << 6) + k;
#pragma unroll
      for (int r = 0; r < 4; ++r) {
        float val = acc[mt][nt][r] + xin[off + (size_t)r * 768];
        x2bf[off + (size_t)r * 768] = f2bf(val);
      }
    }
  }
}

extern "C" void kernel_launch(void* const* d_in, const int* in_sizes, int n_in,
                              void* d_out, int out_size, void* d_ws, size_t ws_size,
                              hipStream_t stream) {
  const float* x = (const float*)d_in[0];
  const float* ln1_s = (const float*)d_in[1];
  const float* ln1_b = (const float*)d_in[2];
  const float* Wv = (const float*)d_in[3];
  const float* alpha = (const float*)d_in[4];
  const float* Wf = (const float*)d_in[5];
  const float* bf = (const float*)d_in[6];
  const float* lnf_s = (const float*)d_in[7];
  const float* lnf_b = (const float*)d_in[8];
  float* out = (float*)d_out;

  char* ws = (char*)d_ws;
  unsigned short* slotA = (unsigned short*)ws;                   // xn -> z1
  unsigned short* Vt = (unsigned short*)(ws + 25165824);         // Vt -> gbf
  unsigned short* gbf = Vt;
  unsigned short* slotX = (unsigned short*)(ws + 50331648);      // x2 bf16
  unsigned short* W2t = (unsigned short*)(ws + 75497472);
  unsigned short* Wft = (unsigned short*)(ws + 76677120);

  // 128KB dynamic LDS for the 256x256 cores
  hipFuncSetAttribute((const void*)gemm1_256,
                      hipFuncAttributeMaxDynamicSharedMemorySize, 131072);
  hipFuncSetAttribute((const void*)gemmf_256,
                      hipFuncAttributeMaxDynamicSharedMemorySize, 131072);

  pack_w2t<<<2304, 256, 0, stream>>>(Wv, W2t);
  pack_wft<<<4608, 256, 0, stream>>>(Wf, Wft);

  ln1_kernel<<<4096, 256, 0, stream>>>(x, ln1_s, ln1_b, slotA);
  gemm1_256<<<192, 512, 131072, stream>>>(slotA, W2t, Vt);
  circ_kernel<<<768, 256, 0, stream>>>(alpha, Vt, x, slotX);
  gemmf_256<<<192, 512, 131072, stream>>>(slotX, Wft, bf, gbf);
  lnswish_kernel<<<4096, 256, 0, stream>>>(gbf, lnf_s, lnf_b, slotA);
  gemmf_256<<<192, 512, 131072, stream>>>(slotA, Wft + 589824, bf + 768, gbf);
  final_kernel<<<4096, 256, 0, stream>>>(gbf, lnf_s + 768, lnf_b + 768, slotX, out);
}

// Round 2
// 270.312 us; speedup vs baseline: 1.0456x; 1.0300x over previous
//
#include <hip/hip_runtime.h>
#include <cstdint>
#include <cstddef>

// B=16, N=1024, D=768, H=12, HS=64, L=2
// R8 changes vs R7:
//  - circ ported to 256x256 / BK=64 / 8-wave / 8-phase counted-vmcnt schedule
//    (circ256_kernel). A-side from 8 shifted LDS alpha copies (window 1288
//    shorts per copy for 256-row tiles, OFF=769); B-side 2-buffer, 1 g2l16
//    call per phase, BARV(2) counted waits at P3/P7. 86KB dynamic LDS.
//    192 blocks (12 heads x 16 tiles), XCD-swizzled for Vt_h L2 reuse.
//  - pack_w2t/pack_wft merged into pack_all (one launch).
//  - dense gemm1/gemmf 256-cores unchanged from R7.
//
// ws layout (bytes): unchanged.
//  [0, 25165824)          slotA : xn_bf16 -> z1_bf16
//  [25165824, 50331648)   Vt    : gemm1 out ; reused as gbf after circ
//  [50331648, 75497472)   slotX : x2_bf16 (circ out, read by gemmf1 + final)
//  [75497472, 76677120)   W2t
//  [76677120, 79036416)   Wft

typedef __attribute__((ext_vector_type(8))) short bf16x8;
typedef __attribute__((ext_vector_type(4))) float f32x4;
typedef __attribute__((ext_vector_type(4))) unsigned short us4;

__device__ __forceinline__ unsigned short f2bf(float f) {
  unsigned int u = __builtin_bit_cast(unsigned int, f);
  u += 0x7FFFu + ((u >> 16) & 1u);
  return (unsigned short)(u >> 16);
}
__device__ __forceinline__ float bf2f(unsigned short u) {
  return __builtin_bit_cast(float, (unsigned int)u << 16);
}

__device__ __forceinline__ void g2l16(const void* g, void* l) {
  __builtin_amdgcn_global_load_lds(
      (const __attribute__((address_space(1))) unsigned int*)g,
      (__attribute__((address_space(3))) unsigned int*)l,
      16, 0, 0);
}

#define BARX asm volatile("s_waitcnt lgkmcnt(0)\n\ts_barrier" ::: "memory")
#define BARV(n) asm volatile("s_waitcnt vmcnt(" #n ") lgkmcnt(0)\n\ts_barrier" ::: "memory")

// ---------------- pack kernel (merged) ----------------
__global__ __launch_bounds__(256) void pack_all(const float* __restrict__ Wv,
                                                const float* __restrict__ Wf,
                                                unsigned short* __restrict__ W2t,
                                                unsigned short* __restrict__ Wft) {
  int bid = blockIdx.x;
  if (bid < 2304) {
    int o = bid * 256 + threadIdx.x;
    int np = o / 768, d = o - np * 768;
    int h = np >> 6, k = np & 63;
    W2t[o] = f2bf(Wv[h * 49152 + d * 64 + k]);
  } else {
    int o = (bid - 2304) * 256 + threadIdx.x;
    int l = o / 589824, rem = o - l * 589824;
    int np = rem / 768, d = rem - np * 768;
    Wft[o] = f2bf(Wf[l * 589824 + d * 768 + np]);
  }
}

// ---------------- row kernels ----------------
__device__ __forceinline__ void wave_reduce2(float& s, float& s2) {
#pragma unroll
  for (int off = 32; off > 0; off >>= 1) {
    s += __shfl_down(s, off);
    s2 += __shfl_down(s2, off);
  }
  s = __shfl(s, 0);
  s2 = __shfl(s2, 0);
}

__global__ __launch_bounds__(256) void ln1_kernel(const float* __restrict__ x,
                                                  const float* __restrict__ sc,
                                                  const float* __restrict__ bi,
                                                  unsigned short* __restrict__ out) {
  int row = blockIdx.x * 4 + (threadIdx.x >> 6);
  int lane = threadIdx.x & 63;
  size_t base = (size_t)row * 768;
  float4 v[3];
#pragma unroll
  for (int j = 0; j < 3; ++j) v[j] = *(const float4*)(x + base + lane * 4 + j * 256);
  float s = 0.f, s2 = 0.f;
#pragma unroll
  for (int j = 0; j < 3; ++j) {
    s += v[j].x + v[j].y + v[j].z + v[j].w;
    s2 += v[j].x * v[j].x + v[j].y * v[j].y + v[j].z * v[j].z + v[j].w * v[j].w;
  }
  wave_reduce2(s, s2);
  float mu = s * (1.0f / 768.0f);
  float var = s2 * (1.0f / 768.0f) - mu * mu;
  float r = rsqrtf(var + 1e-6f);
#pragma unroll
  for (int j = 0; j < 3; ++j) {
    int d = lane * 4 + j * 256;
    float4 scv = *(const float4*)(sc + d);
    float4 biv = *(const float4*)(bi + d);
    us4 o;
    o[0] = f2bf((v[j].x - mu) * r * scv.x + biv.x);
    o[1] = f2bf((v[j].y - mu) * r * scv.y + biv.y);
    o[2] = f2bf((v[j].z - mu) * r * scv.z + biv.z);
    o[3] = f2bf((v[j].w - mu) * r * scv.w + biv.w);
    *(us4*)(out + base + d) = o;
  }
}

__global__ __launch_bounds__(256) void lnswish_kernel(const unsigned short* __restrict__ g,
                                                      const float* __restrict__ sc,
                                                      const float* __restrict__ bi,
                                                      unsigned short* __restrict__ out) {
  int row = blockIdx.x * 4 + (threadIdx.x >> 6);
  int lane = threadIdx.x & 63;
  size_t base = (size_t)row * 768;
  float v[3][4];
#pragma unroll
  for (int j = 0; j < 3; ++j) {
    us4 gv = *(const us4*)(g + base + lane * 4 + j * 256);
#pragma unroll
    for (int q = 0; q < 4; ++q) v[j][q] = bf2f(gv[q]);
  }
  float s = 0.f, s2 = 0.f;
#pragma unroll
  for (int j = 0; j < 3; ++j)
#pragma unroll
    for (int q = 0; q < 4; ++q) { s += v[j][q]; s2 += v[j][q] * v[j][q]; }
  wave_reduce2(s, s2);
  float mu = s * (1.0f / 768.0f);
  float var = s2 * (1.0f / 768.0f) - mu * mu;
  float r = rsqrtf(var + 1e-6f);
#pragma unroll
  for (int j = 0; j < 3; ++j) {
    int d = lane * 4 + j * 256;
    float4 scv = *(const float4*)(sc + d);
    float4 biv = *(const float4*)(bi + d);
    const float* scp = &scv.x;
    const float* bip = &biv.x;
    us4 o;
#pragma unroll
    for (int q = 0; q < 4; ++q) {
      float z = (v[j][q] - mu) * r * scp[q] + bip[q];
      o[q] = f2bf(z / (1.0f + __expf(-z)));
    }
    *(us4*)(out + base + d) = o;
  }
}

__global__ __launch_bounds__(256) void final_kernel(const unsigned short* __restrict__ g,
                                                    const float* __restrict__ sc,
                                                    const float* __restrict__ bi,
                                                    const unsigned short* __restrict__ x2,
                                                    float* __restrict__ out) {
  int row = blockIdx.x * 4 + (threadIdx.x >> 6);
  int lane = threadIdx.x & 63;
  size_t base = (size_t)row * 768;
  float v[3][4];
#pragma unroll
  for (int j = 0; j < 3; ++j) {
    us4 gv = *(const us4*)(g + base + lane * 4 + j * 256);
#pragma unroll
    for (int q = 0; q < 4; ++q) v[j][q] = bf2f(gv[q]);
  }
  float s = 0.f, s2 = 0.f;
#pragma unroll
  for (int j = 0; j < 3; ++j)
#pragma unroll
    for (int q = 0; q < 4; ++q) { s += v[j][q]; s2 += v[j][q] * v[j][q]; }
  wave_reduce2(s, s2);
  float mu = s * (1.0f / 768.0f);
  float var = s2 * (1.0f / 768.0f) - mu * mu;
  float r = rsqrtf(var + 1e-6f);
#pragma unroll
  for (int j = 0; j < 3; ++j) {
    int d = lane * 4 + j * 256;
    float4 scv = *(const float4*)(sc + d);
    float4 biv = *(const float4*)(bi + d);
    us4 xv = *(const us4*)(x2 + base + d);
    const float* scp = &scv.x;
    const float* bip = &biv.x;
    float4 o;
    float* op = &o.x;
#pragma unroll
    for (int q = 0; q < 4; ++q) {
      float z = (v[j][q] - mu) * r * scp[q] + bip[q];
      float sw = z / (1.0f + __expf(-z));
      float t = sw + bf2f(xv[q]);
      float ax = fabsf(t);
      op[q] = ax + __logf(1.0f + __expf(-2.0f * ax)) - 0.69314718055994531f;
    }
    *(float4*)(out + base + d) = o;
  }
}

// ---------- 256x256 8-phase dense GEMM core (unchanged from R7) ----------
template <int K>
__device__ __forceinline__ void gemm256(const unsigned short* __restrict__ A,
                                        const unsigned short* __restrict__ Bt,
                                        int m0, int n0, unsigned short* lds,
                                        f32x4 acc[8][4]) {
  const int tid = threadIdx.x;
  const int lane = tid & 63;
  const int wid = tid >> 6;
  const int wm = (wid >> 2) << 6;
  const int wn = (wid & 3) << 5;
  const int fm = lane & 15, fq = lane >> 4;
  const int srow = tid >> 3;
  const int sslot = (tid & 7) ^ (srow & 7);
  const size_t abase = (size_t)(m0 + srow) * K + (sslot << 3);
  const size_t bbase = (size_t)(n0 + srow) * K + (sslot << 3);

  bf16x8 aq[4][2], bq[4][2];

#define STG_A(kt, bb, c)                                                     \
  g2l16(A + abase + (size_t)((c) << 6) * K + ((kt) << 6),                    \
        lds + ((bb) << 15) + ((c) << 12) + (tid << 3))
#define STG_B(kt, bb, c)                                                     \
  g2l16(Bt + bbase + (size_t)((c) << 6) * K + ((kt) << 6),                   \
        lds + ((bb) << 15) + 16384 + ((c) << 12) + (tid << 3))
#define LDA(bb, mh)                                                          \
  _Pragma("unroll") for (int mt = 0; mt < 4; ++mt) {                         \
    const unsigned short* p =                                                \
        lds + ((bb) << 15) + (wm + ((mh) << 7) + (mt << 4) + fm) * 64;       \
    _Pragma("unroll") for (int kk = 0; kk < 2; ++kk)                         \
      aq[mt][kk] = *(const bf16x8*)(p + ((((kk << 2) + fq) ^ (fm & 7)) << 3)); \
  }
#define LDB(bb, nh)                                                          \
  _Pragma("unroll") for (int nt = 0; nt < 2; ++nt) {                         \
    const unsigned short* p = lds + ((bb) << 15) + 16384 +                   \
                              (wn + ((nh) << 7) + (nt << 4) + fm) * 64;      \
    _Pragma("unroll") for (int kk = 0; kk < 2; ++kk)                         \
      bq[((nh) << 1) + nt][kk] =                                             \
          *(const bf16x8*)(p + ((((kk << 2) + fq) ^ (fm & 7)) << 3));        \
  }
#define MMX(mh, nh)                                                          \
  {                                                                          \
    __builtin_amdgcn_s_setprio(1);                                           \
    _Pragma("unroll") for (int mt = 0; mt < 4; ++mt)                         \
    _Pragma("unroll") for (int nt = 0; nt < 2; ++nt)                         \
    _Pragma("unroll") for (int kk = 0; kk < 2; ++kk)                         \
      acc[((mh) << 2) + mt][((nh) << 1) + nt] =                              \
          __builtin_amdgcn_mfma_f32_16x16x32_bf16(                           \
              aq[mt][kk], bq[((nh) << 1) + nt][kk],                          \
              acc[((mh) << 2) + mt][((nh) << 1) + nt], 0, 0, 0);             \
    __builtin_amdgcn_s_setprio(0);                                           \
  }

  constexpr int NT = K >> 6;
  STG_A(0, 0, 0); STG_A(0, 0, 1); STG_A(0, 0, 2); STG_A(0, 0, 3);
  STG_B(0, 0, 0); STG_B(0, 0, 1); STG_B(0, 0, 2); STG_B(0, 0, 3);
  STG_A(1, 1, 0); STG_A(1, 1, 1);
  STG_B(1, 1, 0); STG_B(1, 1, 1);
  BARV(4);

  for (int t = 0; t < (NT >> 1) - 1; ++t) {
    const int k1 = 2 * t + 1, k2 = 2 * t + 2, k3 = 2 * t + 3;
    LDA(0, 0); LDB(0, 0);
    STG_A(k1, 1, 2); STG_A(k1, 1, 3);
    MMX(0, 0); BARX;
    LDB(0, 1);
    STG_B(k1, 1, 2); STG_B(k1, 1, 3);
    MMX(0, 1); BARX;
    LDA(0, 1);
    STG_A(k2, 0, 0); STG_A(k2, 0, 1);
    MMX(1, 0); BARX;
    STG_B(k2, 0, 0); STG_B(k2, 0, 1);
    MMX(1, 1); BARV(4);
    LDA(1, 0); LDB(1, 0);
    STG_A(k2, 0, 2); STG_A(k2, 0, 3);
    MMX(0, 0); BARX;
    LDB(1, 1);
    STG_B(k2, 0, 2); STG_B(k2, 0, 3);
    MMX(0, 1); BARX;
    LDA(1, 1);
    STG_A(k3, 1, 0); STG_A(k3, 1, 1);
    MMX(1, 0); BARX;
    STG_B(k3, 1, 0); STG_B(k3, 1, 1);
    MMX(1, 1); BARV(4);
  }
  {
    const int k1 = NT - 1;
    LDA(0, 0); LDB(0, 0);
    STG_A(k1, 1, 2); STG_A(k1, 1, 3);
    MMX(0, 0); BARX;
    LDB(0, 1);
    STG_B(k1, 1, 2); STG_B(k1, 1, 3);
    MMX(0, 1); BARX;
    LDA(0, 1);
    MMX(1, 0); BARX;
    MMX(1, 1);
    BARV(0);
    LDA(1, 0); LDB(1, 0);
    MMX(0, 0); BARX;
    LDB(1, 1);
    MMX(0, 1); BARX;
    LDA(1, 1);
    MMX(1, 0); BARX;
    MMX(1, 1);
  }
#undef STG_A
#undef STG_B
#undef LDA
#undef LDB
#undef MMX
}

__device__ __forceinline__ void decode256(int bid, int& m0, int& n0) {
  int wg = (bid & 7) * 24 + (bid >> 3);
  int mi = wg / 3, ni = wg - mi * 3;
  m0 = mi << 8;
  n0 = ni << 8;
}

// GEMM1: xn @ W2t -> Vt[h][b*64+k][n] (bf16)
__global__ __launch_bounds__(512, 2) void gemm1_256(const unsigned short* __restrict__ A,
                                                    const unsigned short* __restrict__ W2t,
                                                    unsigned short* __restrict__ Vt) {
  extern __shared__ unsigned short lds[];
  f32x4 acc[8][4] = {};
  int m0, n0;
  decode256(blockIdx.x, m0, n0);
  gemm256<768>(A, W2t, m0, n0, lds, acc);
  const int lane = threadIdx.x & 63, wid = threadIdx.x >> 6;
  const int wm = (wid >> 2) << 6, wn = (wid & 3) << 5;
  const int fm = lane & 15, fq = lane >> 4;
#pragma unroll
  for (int ai = 0; ai < 8; ++ai) {
    int rowb = m0 + wm + ((ai >> 2) << 7) + ((ai & 3) << 4) + (fq << 2);
    int b = rowb >> 10, n = rowb & 1023;
#pragma unroll
    for (int nj = 0; nj < 4; ++nj) {
      int col = n0 + wn + ((nj >> 1) << 7) + ((nj & 1) << 4) + fm;
      int h = col >> 6, ck = col & 63;
      size_t off = ((size_t)h << 20) + (size_t)((b << 6) + ck) * 1024 + n;
      us4 v;
#pragma unroll
      for (int r = 0; r < 4; ++r) v[r] = f2bf(acc[ai][nj][r]);
      *(us4*)(Vt + off) = v;
    }
  }
}

// FFN GEMM: A(bf16) @ Wt + bias -> g (bf16)
__global__ __launch_bounds__(512, 2) void gemmf_256(const unsigned short* __restrict__ A,
                                                    const unsigned short* __restrict__ Bt,
                                                    const float* __restrict__ bias,
                                                    unsigned short* __restrict__ g) {
  extern __shared__ unsigned short lds[];
  f32x4 acc[8][4] = {};
  int m0, n0;
  decode256(blockIdx.x, m0, n0);
  gemm256<768>(A, Bt, m0, n0, lds, acc);
  const int lane = threadIdx.x & 63, wid = threadIdx.x >> 6;
  const int wm = (wid >> 2) << 6, wn = (wid & 3) << 5;
  const int fm = lane & 15, fq = lane >> 4;
#pragma unroll
  for (int ai = 0; ai < 8; ++ai) {
    int rowb = m0 + wm + ((ai >> 2) << 7) + ((ai & 3) << 4) + (fq << 2);
#pragma unroll
    for (int nj = 0; nj < 4; ++nj) {
      int col = n0 + wn + ((nj >> 1) << 7) + ((nj & 1) << 4) + fm;
      float bc = bias[col];
#pragma unroll
      for (int r = 0; r < 4; ++r)
        g[(size_t)(rowb + r) * 768 + col] = f2bf(acc[ai][nj][r] + bc);
    }
  }
}

// ---------- circ 256x256 8-phase (R8) ----------
// A circulant: C[i][j] = alpha[h][(i-j)&1023]. With Arev[t]=alpha[(-t)&1023],
// C[i][j] = Arev[j-i]; frag needs 8 consecutive j at fixed i -> contiguous.
// sAc[c][u] = alpha[h][(m0 - 769 - u - c)&1023], read bf16x8 at c*1288+(d&~7),
// d = k + 255 - rl, c = d&7  (derivation: value at elem s = alpha[(m0+rl-k-s)
// &1023] = C[m0+rl][k+s]).  d in [0,1271], window 1280 (+8 pad).
// B: Vt_h rows (b*64+k), stride 1024; 2-buffer, 4 chunks/tile, 1 chunk/phase.
// Region safety: staged chunk's last LDS read is >=2 barriers (with
// lgkmcnt(0)) before the g2l16 issue; counted BARV(2) at P3/P7 lands tiles
// exactly one K-tile ahead (invariant: 2 outstanding at iter entry).
__global__ __launch_bounds__(512, 2) void circ256_kernel(const float* __restrict__ alpha,
                                                         const unsigned short* __restrict__ Vt,
                                                         const float* __restrict__ xin,
                                                         unsigned short* __restrict__ x2bf) {
  extern __shared__ unsigned short lds[];
  unsigned short* sAc = lds;          // 8*1288 = 10304 shorts
  unsigned short* sB = lds + 10304;   // 2*16384 shorts
  f32x4 acc[8][4] = {};

  int wg = (blockIdx.x & 7) * 24 + (blockIdx.x >> 3);
  int h = wg >> 4, tt = wg & 15;
  int m0 = (tt >> 2) << 8, n0 = (tt & 3) << 8;

  const int tid = threadIdx.x;
  const int lane = tid & 63, wid = tid >> 6;
  const int wm = (wid >> 2) << 6, wn = (wid & 3) << 5;
  const int fm = lane & 15, fq = lane >> 4;
  const int srow = tid >> 3;
  const int sslot = (tid & 7) ^ (srow & 7);

  const float* ah = alpha + (h << 10);
#pragma unroll
  for (int c = 0; c < 8; ++c)
    for (int u = tid; u < 1280; u += 512)
      sAc[c * 1288 + u] = f2bf(ah[(m0 - 769 - u - c) & 1023]);

  const unsigned short* Bt = Vt + ((size_t)h << 20);
  const size_t bbase = (size_t)(n0 + srow) * 1024 + (sslot << 3);

  bf16x8 aq[4][2], bq[4][2];

#define CSTG(kt, bb, c)                                                      \
  g2l16(Bt + bbase + (size_t)((c) << 6) * 1024 + ((kt) << 6),                \
        sB + ((bb) << 14) + ((c) << 12) + (tid << 3))
#define CLDA(kt, mh)                                                         \
  _Pragma("unroll") for (int mt = 0; mt < 4; ++mt)                           \
  _Pragma("unroll") for (int kk = 0; kk < 2; ++kk) {                         \
    int d_ = ((kt) << 6) + (kk << 5) + (fq << 3) + 255 -                     \
             (wm + ((mh) << 7) + (mt << 4) + fm);                            \
    int c_ = d_ & 7;                                                         \
    aq[mt][kk] = *(const bf16x8*)(sAc + c_ * 1288 + (d_ - c_));              \
  }
#define CLDB(bb, nh)                                                         \
  _Pragma("unroll") for (int nt = 0; nt < 2; ++nt) {                         \
    const unsigned short* p =                                                \
        sB + ((bb) << 14) + (wn + ((nh) << 7) + (nt << 4) + fm) * 64;        \
    _Pragma("unroll") for (int kk = 0; kk < 2; ++kk)                         \
      bq[((nh) << 1) + nt][kk] =                                             \
          *(const bf16x8*)(p + ((((kk << 2) + fq) ^ (fm & 7)) << 3));        \
  }
#define CMMX(mh, nh)                                                         \
  {                                                                          \
    __builtin_amdgcn_s_setprio(1);                                           \
    _Pragma("unroll") for (int mt = 0; mt < 4; ++mt)                         \
    _Pragma("unroll") for (int nt = 0; nt < 2; ++nt)                         \
    _Pragma("unroll") for (int kk = 0; kk < 2; ++kk)                         \
      acc[((mh) << 2) + mt][((nh) << 1) + nt] =                              \
          __builtin_amdgcn_mfma_f32_16x16x32_bf16(                           \
              aq[mt][kk], bq[((nh) << 1) + nt][kk],                          \
              acc[((mh) << 2) + mt][((nh) << 1) + nt], 0, 0, 0);             \
    __builtin_amdgcn_s_setprio(0);                                           \
  }

  // prologue: tile0 all 4 chunks -> buf0; tile1 c0,c1 -> buf1
  CSTG(0, 0, 0); CSTG(0, 0, 1); CSTG(0, 0, 2); CSTG(0, 0, 3);
  CSTG(1, 1, 0); CSTG(1, 1, 1);
  BARV(2);  // tile0 landed (also covers sAc ds_write drain via lgkmcnt+barrier)

  for (int it = 0; it < 7; ++it) {
    const int k0 = 2 * it, k1 = 2 * it + 1, k2 = 2 * it + 2, k3 = 2 * it + 3;
    CLDA(k0, 0); CLDB(0, 0);
    CSTG(k1, 1, 2);
    CMMX(0, 0); BARX;
    CLDB(0, 1);
    CSTG(k1, 1, 3);
    CMMX(0, 1); BARX;
    CLDA(k0, 1);
    CSTG(k2, 0, 0);
    CMMX(1, 0); BARX;
    CSTG(k2, 0, 1);
    CMMX(1, 1); BARV(2);   // tile k1 fully landed; k2.c0/c1 in flight
    CLDA(k1, 0); CLDB(1, 0);
    CSTG(k2, 0, 2);
    CMMX(0, 0); BARX;
    CLDB(1, 1);
    CSTG(k2, 0, 3);
    CMMX(0, 1); BARX;
    CLDA(k1, 1);
    CSTG(k3, 1, 0);
    CMMX(1, 0); BARX;
    CSTG(k3, 1, 1);
    CMMX(1, 1); BARV(2);   // tile k2 fully landed; k3.c0/c1 in flight
  }
  // peeled: tiles 14 (buf0), 15 (buf1)
  CLDA(14, 0); CLDB(0, 0);
  CSTG(15, 1, 2);
  CMMX(0, 0); BARX;
  CLDB(0, 1);
  CSTG(15, 1, 3);
  CMMX(0, 1); BARX;
  CLDA(14, 1);
  CMMX(1, 0); BARX;
  CMMX(1, 1);
  BARV(0);               // drain: tile15 all landed
  CLDA(15, 0); CLDB(1, 0);
  CMMX(0, 0); BARX;
  CLDB(1, 1);
  CMMX(0, 1); BARX;
  CLDA(15, 1);
  CMMX(1, 0); BARX;
  CMMX(1, 1);
#undef CSTG
#undef CLDA
#undef CLDB
#undef CMMX

  // epilogue: x2 = x + y (bf16)
#pragma unroll
  for (int ai = 0; ai < 8; ++ai) {
    int i = m0 + wm + ((ai >> 2) << 7) + ((ai & 3) << 4) + (fq << 2);
#pragma unroll
    for (int nj = 0; nj < 4; ++nj) {
      int col = n0 + wn + ((nj >> 1) << 7) + ((nj & 1) << 4) + fm;
      int b = col >> 6, k = col & 63;
      size_t off = ((size_t)(b << 10) + i) * 768 + (h << 6) + k;
#pragma unroll
      for (int r = 0; r < 4; ++r) {
        float val = acc[ai][nj][r] + xin[off + (size_t)r * 768];
        x2bf[off + (size_t)r * 768] = f2bf(val);
      }
    }
  }
}

extern "C" void kernel_launch(void* const* d_in, const int* in_sizes, int n_in,
                              void* d_out, int out_size, void* d_ws, size_t ws_size,
                              hipStream_t stream) {
  const float* x = (const float*)d_in[0];
  const float* ln1_s = (const float*)d_in[1];
  const float* ln1_b = (const float*)d_in[2];
  const float* Wv = (const float*)d_in[3];
  const float* alpha = (const float*)d_in[4];
  const float* Wf = (const float*)d_in[5];
  const float* bf = (const float*)d_in[6];
  const float* lnf_s = (const float*)d_in[7];
  const float* lnf_b = (const float*)d_in[8];
  float* out = (float*)d_out;

  char* ws = (char*)d_ws;
  unsigned short* slotA = (unsigned short*)ws;
  unsigned short* Vt = (unsigned short*)(ws + 25165824);
  unsigned short* gbf = Vt;
  unsigned short* slotX = (unsigned short*)(ws + 50331648);
  unsigned short* W2t = (unsigned short*)(ws + 75497472);
  unsigned short* Wft = (unsigned short*)(ws + 76677120);

  hipFuncSetAttribute((const void*)gemm1_256,
                      hipFuncAttributeMaxDynamicSharedMemorySize, 131072);
  hipFuncSetAttribute((const void*)gemmf_256,
                      hipFuncAttributeMaxDynamicSharedMemorySize, 131072);
  hipFuncSetAttribute((const void*)circ256_kernel,
                      hipFuncAttributeMaxDynamicSharedMemorySize, 86144);

  pack_all<<<6912, 256, 0, stream>>>(Wv, Wf, W2t, Wft);

  ln1_kernel<<<4096, 256, 0, stream>>>(x, ln1_s, ln1_b, slotA);
  gemm1_256<<<192, 512, 131072, stream>>>(slotA, W2t, Vt);
  circ256_kernel<<<192, 512, 86144, stream>>>(alpha, Vt, x, slotX);
  gemmf_256<<<192, 512, 131072, stream>>>(slotX, Wft, bf, gbf);
  lnswish_kernel<<<4096, 256, 0, stream>>>(gbf, lnf_s, lnf_b, slotA);
  gemmf_256<<<192, 512, 131072, stream>>>(slotA, Wft + 589824, bf + 768, gbf);
  final_kernel<<<4096, 256, 0, stream>>>(gbf, lnf_s + 768, lnf_b + 768, slotX, out);
}